// Round 6
// baseline (5833.981 us; speedup 1.0000x reference)
//
#include <hip/hip_runtime.h>
#include <math.h>

#define NB 256
#define TT 64
#define DD 1024
#define HH 1024

typedef __attribute__((ext_vector_type(8))) short short8;
typedef __attribute__((ext_vector_type(4))) float floatx4;

__device__ inline unsigned short f2bf(float f) {
    unsigned int u = __builtin_bit_cast(unsigned int, f);
    u += 0x7fffu + ((u >> 16) & 1u);
    return (unsigned short)(u >> 16);
}
__device__ inline float bf2f(unsigned int h16) {
    unsigned int u = h16 << 16;
    return __builtin_bit_cast(float, u);
}

__device__ inline void async_copy16(const unsigned short* g, unsigned short* l) {
    __builtin_amdgcn_global_load_lds(
        (const __attribute__((address_space(1))) unsigned int*)(g),
        (__attribute__((address_space(3))) unsigned int*)(l), 16, 0, 0);
}

// device-scope group barrier for 64 blocks (one mi-group). Monotonic counter.
// __threadfence per thread: (a) publishes this thread's global stores device-wide,
// (b) drains vmcnt to 0 -> the counted-vmcnt asm in the GEMM phase stays exact.
__device__ inline void groupsync(unsigned* ctr, unsigned target) {
    __threadfence();
    __syncthreads();
    if (threadIdx.x == 0) {
        __hip_atomic_fetch_add(ctr, 1u, __ATOMIC_RELEASE, __HIP_MEMORY_SCOPE_AGENT);
        while (__hip_atomic_load(ctr, __ATOMIC_ACQUIRE, __HIP_MEMORY_SCOPE_AGENT) < target)
            __builtin_amdgcn_s_sleep(2);
    }
    __syncthreads();
}

// ---------------- conv W: fp32 [k][4096] -> bf16 B-fragment tiles, N_b=64 ----------
// Tile (nj 0..63, kc 0..47): 512 units of 16B; unit = kq*64 + cc (kq 0..7, cc 0..63);
// holds W[k = kc*64+kq*8 + j][col = (cc>>4)*1024 + nj*16 + (cc&15)], j=0..7.
__global__ void k_convW(const float* __restrict__ Wh,
                        const float* __restrict__ Wattn,
                        const float* __restrict__ Wx,
                        unsigned short* __restrict__ Wsw) {
    int u = blockIdx.x * 256 + threadIdx.x;  // 0 .. 64*48*512-1
    int tile = u >> 9;
    int nj = tile / 48, kc = tile % 48;
    int within = u & 511;
    int kq = within >> 6, cc = within & 63;
    int k = kc * 64 + kq * 8;
    int col = (cc >> 4) * 1024 + nj * 16 + (cc & 15);
    const float* src;
    if (k < 1024)       src = Wh    + (size_t)k * 4096 + col;
    else if (k < 2048)  src = Wattn + (size_t)(k - 1024) * 4096 + col;
    else                src = Wx    + (size_t)(k - 2048) * 4096 + col;
    unsigned int w[4];
#pragma unroll
    for (int j = 0; j < 4; ++j) {
        unsigned int lo = f2bf(src[(size_t)(2 * j) * 4096]);
        unsigned int hi = f2bf(src[(size_t)(2 * j + 1) * 4096]);
        w[j] = lo | (hi << 16);
    }
    ((uint4*)Wsw)[u] = make_uint4(w[0], w[1], w[2], w[3]);
}

// ---------------- conv x: fp32 [m][t][d] -> bf16 A-fragment layout -----------------
// xF unit index = t*32768 + kq*256 + m ; holds x[m][t][kq*8 + j], j=0..7.
__global__ __launch_bounds__(256) void k_convX(const float* __restrict__ x,
                                               unsigned short* __restrict__ xF) {
    const int t  = blockIdx.x >> 4;   // 0..63
    const int mb = blockIdx.x & 15;   // 0..15 (16 batch rows per block)
    const int tid = threadIdx.x;
    __shared__ unsigned short xb[16][1032];  // row stride 1032 shorts (pad)

#pragma unroll
    for (int mm = 0; mm < 16; ++mm) {
        int m = mb * 16 + mm;
        const float4* src = (const float4*)(x + (size_t)m * (TT * DD) + (size_t)t * DD);
        float4 v = src[tid];  // d = tid*4 .. tid*4+3
        unsigned int w0 = f2bf(v.x) | (f2bf(v.y) << 16);
        unsigned int w1 = f2bf(v.z) | (f2bf(v.w) << 16);
        *(uint2*)&xb[mm][tid * 4] = make_uint2(w0, w1);
    }
    __syncthreads();

#pragma unroll
    for (int i = 0; i < 8; ++i) {
        int u = i * 256 + tid;
        int kq = u >> 4, mm = u & 15;
        uint4 val = *(const uint4*)&xb[mm][kq * 8];
        size_t gu = (size_t)t * 32768 + (size_t)kq * 256 + mb * 16 + mm;
        ((uint4*)xF)[gu] = val;
    }
}

// ---------------- conv A -> bf16, plus h0 = c0 = mean; zero sync counters ----------
__global__ void k_convA_init(const float* __restrict__ A,
                             unsigned short* __restrict__ Abf,
                             float* __restrict__ h0,
                             float* __restrict__ c,
                             unsigned* __restrict__ syncc) {
    int idx = blockIdx.x * 256 + threadIdx.x;  // n*1024 + h
    if (blockIdx.x == 0 && threadIdx.x < 4) syncc[threadIdx.x * 256] = 0u;
    const float4* ap = (const float4*)(A + (size_t)idx * 16);
    float4 v0 = ap[0], v1 = ap[1], v2 = ap[2], v3 = ap[3];
    float vs[16] = {v0.x, v0.y, v0.z, v0.w, v1.x, v1.y, v1.z, v1.w,
                    v2.x, v2.y, v2.z, v2.w, v3.x, v3.y, v3.z, v3.w};
    float s = 0.f;
    unsigned int w[8];
#pragma unroll
    for (int j = 0; j < 8; ++j) {
        s += vs[2 * j] + vs[2 * j + 1];
        w[j] = f2bf(vs[2 * j]) | (f2bf(vs[2 * j + 1]) << 16);
    }
    ((uint4*)Abf)[idx * 2]     = make_uint4(w[0], w[1], w[2], w[3]);
    ((uint4*)Abf)[idx * 2 + 1] = make_uint4(w[4], w[5], w[6], w[7]);
    s *= (1.f / 16.f);
    h0[idx] = s;
    c[idx] = s;
}

// ---------------- k_fused: PERSISTENT 64-step loop — attn + GEMM + gates -----------
// One launch replaces 128 (R0-R5 evidence: ~15 us/step was fixed overhead: launch
// gaps + attn kernel + Abf re-read; the K-loop itself is only ~4-5 us/step).
// Grid = 256 blocks (1/CU, all co-resident). bid -> (g = bid>>6, nj = bid&63).
// Dependencies close WITHIN each 64-block mi-group g:
//   phase1: block computes attn for row n = g*64+nj -> lhsF rows of group g
//   phase2: GEMM tile (nj, mi=g), reads lhsF rows g*64..g*64+63, writes out/c rows
//   attn(t+1) reads out rows of group g (written by group g's phase2)
// -> per-group 64-block sync (device-scope atomic counter), 2 per step. Groups
// drift independently. a[4][16] (A_flat slice) hoisted to VGPRs once: t-invariant,
// removes the 8 MB/step Abf re-read the old per-step k_attn paid.
// Phase 2 is the verified R0 pipeline byte-for-byte (4 buf global_load_lds,
// vmcnt(8) cadence; groupsync's threadfence guarantees vmcnt==0 at phase entry).
__global__ __launch_bounds__(256, 1) void k_fused(
    const unsigned short* __restrict__ Abf,
    const unsigned short* __restrict__ xF,
    const unsigned short* __restrict__ Wsw,
    const float* __restrict__ b,
    const float* __restrict__ h0,
    float* __restrict__ c,
    unsigned short* __restrict__ lhsF,
    unsigned* __restrict__ syncc,
    float* __restrict__ out) {
    const int bid = blockIdx.x;
    const int g = bid >> 6;          // mi-group 0..3
    const int nj = bid & 63;
    const int n = g * 64 + nj;       // attn row owned by this block
    const int mi = g;
    unsigned* ctr = syncc + g * 256; // 1 KB apart, one counter per group

    const int tid = threadIdx.x;
    const int lane = tid & 63, wave = tid >> 6;
    const int wm = wave & 1, wn = wave >> 1;
    const int l15 = lane & 15, quad = lane >> 4;
    const int waveBase = tid & ~63;

    __shared__ __align__(16) unsigned short lds[4 * 8192];  // 64 KB (GEMM + epilogue)
    __shared__ float wred[4 * 16];                          // attn reduction

    // ---- hoisted t-invariants ----
    // A_flat slice for row n: thread tid holds features tid*4..tid*4+3 x 16 locs
    float a[4][16];
    {
        const uint4* ar = (const uint4*)(Abf + ((size_t)n * 1024 + tid * 4) * 16);
#pragma unroll
        for (int r = 0; r < 4; ++r) {
            uint4 p0 = ar[r * 2], p1 = ar[r * 2 + 1];
            unsigned int ws[8] = {p0.x, p0.y, p0.z, p0.w, p1.x, p1.y, p1.z, p1.w};
#pragma unroll
            for (int j = 0; j < 8; ++j) {
                a[r][2 * j]     = bf2f(ws[j] & 0xffffu);
                a[r][2 * j + 1] = bf2f(ws[j] >> 16);
            }
        }
    }
    const unsigned short* wTile = Wsw + (size_t)nj * (48 * 512 * 8);
    const int j15 = tid & 15;
    const int jj = nj * 16 + j15;
    const float bi = b[jj], bf_ = b[1024 + jj], bo = b[2048 + jj], bg = b[3072 + jj];
    const size_t hu = ((size_t)(tid >> 1) * 256 + n) * 8 + (size_t)(tid & 1) * 4;
    const size_t au = ((size_t)(128 + (tid >> 1)) * 256 + n) * 8 + (size_t)(tid & 1) * 4;

    for (int t = 0; t < TT; ++t) {
        // ================= phase 1: attention for row n =================
        const float* hp = (t == 0) ? (h0 + (size_t)n * HH)
                                   : (out + (size_t)n * (TT * HH) + (size_t)(t - 1) * HH);
        float4 hv = *(const float4*)(hp + tid * 4);
        float hvv[4] = {hv.x, hv.y, hv.z, hv.w};
        float s[16];
#pragma unroll
        for (int l = 0; l < 16; ++l) {
            float tacc = 0.f;
#pragma unroll
            for (int r = 0; r < 4; ++r) tacc += hvv[r] * a[r][l];
            s[l] = tacc;
        }
#pragma unroll
        for (int off = 32; off > 0; off >>= 1) {
#pragma unroll
            for (int l = 0; l < 16; ++l) s[l] += __shfl_xor(s[l], off, 64);
        }
        if (lane == 0) {
#pragma unroll
            for (int l = 0; l < 16; ++l) wred[wave * 16 + l] = s[l];
        }
        __syncthreads();
        const float scale = 0.03125f;  // 1/sqrt(1024)
        float sv[16];
#pragma unroll
        for (int l = 0; l < 16; ++l)
            sv[l] = (wred[l] + wred[16 + l] + wred[32 + l] + wred[48 + l]) * scale;
        __syncthreads();   // wred reusable next step
        float mx = sv[0];
#pragma unroll
        for (int l = 1; l < 16; ++l) mx = fmaxf(mx, sv[l]);
        float e[16], esum = 0.f;
#pragma unroll
        for (int l = 0; l < 16; ++l) { e[l] = __expf(sv[l] - mx); esum += e[l]; }
        float inv = 1.f / esum;
#pragma unroll
        for (int l = 0; l < 16; ++l) e[l] *= inv;
        unsigned short hb[4], ab[4];
#pragma unroll
        for (int r = 0; r < 4; ++r) {
            float acc2 = 0.f;
#pragma unroll
            for (int l = 0; l < 16; ++l) acc2 += a[r][l] * e[l];
            ab[r] = f2bf(acc2);
            hb[r] = f2bf(hvv[r]);
        }
        *(uint2*)(lhsF + hu) = make_uint2(
            (unsigned)hb[0] | ((unsigned)hb[1] << 16),
            (unsigned)hb[2] | ((unsigned)hb[3] << 16));
        *(uint2*)(lhsF + au) = make_uint2(
            (unsigned)ab[0] | ((unsigned)ab[1] << 16),
            (unsigned)ab[2] | ((unsigned)ab[3] << 16));

        groupsync(ctr, 64u * (2 * t + 1));   // lhsF of group g complete

        // ================= phase 2: GEMM (nj, mi) + gates =================
        const unsigned short* xFt = xF + (size_t)t * 262144;

        floatx4 acc[2][2];
#pragma unroll
        for (int mt = 0; mt < 2; ++mt)
#pragma unroll
            for (int nt = 0; nt < 2; ++nt) acc[mt][nt] = (floatx4)0.f;

        auto stage = [&](int kc, int buf) {
            unsigned short* la = lds + (size_t)buf * 8192;
            unsigned short* lb = la + 4096;
            const unsigned short* as_ = (kc < 32)
                ? lhsF + ((size_t)(kc * 8) * 256 + (size_t)mi * 64) * 8
                : xFt + ((size_t)((kc - 32) * 8) * 256 + (size_t)mi * 64) * 8;
#pragma unroll
            for (int i = 0; i < 2; ++i) {
                int idx = i * 256 + tid;
                int kq = idx >> 6, mm = idx & 63;
                async_copy16(as_ + ((size_t)kq * 256 + mm) * 8,
                             la + (size_t)(i * 256 + waveBase) * 8);
            }
            const unsigned short* bs = wTile + (size_t)kc * 512 * 8;
#pragma unroll
            for (int i = 0; i < 2; ++i) {
                int idx = i * 256 + tid;
                async_copy16(bs + (size_t)idx * 8,
                             lb + (size_t)(i * 256 + waveBase) * 8);
            }
        };
        auto compute = [&](int buf) {
            const unsigned short* la = lds + (size_t)buf * 8192;
            const unsigned short* lb = la + 4096;
#pragma unroll
            for (int ks = 0; ks < 2; ++ks) {
                const int kqq = ks * 4 + quad;
                short8 af[2], bfr[2];
#pragma unroll
                for (int mt = 0; mt < 2; ++mt)
                    af[mt] = *(const short8*)(la + (size_t)(kqq * 64 + wm * 32 + mt * 16 + l15) * 8);
#pragma unroll
                for (int nt = 0; nt < 2; ++nt)
                    bfr[nt] = *(const short8*)(lb + (size_t)(kqq * 64 + wn * 32 + nt * 16 + l15) * 8);
#pragma unroll
                for (int mt = 0; mt < 2; ++mt)
#pragma unroll
                    for (int nt = 0; nt < 2; ++nt)
                        acc[mt][nt] = __builtin_amdgcn_mfma_f32_16x16x32_bf16(
                            af[mt], bfr[nt], acc[mt][nt], 0, 0, 0);
            }
        };

        stage(0, 0);
        stage(1, 1);
        stage(2, 2);  // 12 loads/wave outstanding (vmcnt==0 at phase entry via groupsync)

#pragma unroll 4
        for (int kc = 0; kc < 45; ++kc) {
            asm volatile("s_waitcnt vmcnt(8)\n\ts_barrier" ::: "memory");
            stage(kc + 3, (kc + 3) & 3);
            compute(kc & 3);
        }
        asm volatile("s_waitcnt vmcnt(8)\n\ts_barrier" ::: "memory");
        compute(45 & 3);
        asm volatile("s_waitcnt vmcnt(4)\n\ts_barrier" ::: "memory");
        compute(46 & 3);
        asm volatile("s_waitcnt vmcnt(0)\n\ts_barrier" ::: "memory");
        compute(47 & 3);

        // epilogue: exchange 64x64 fp32 tile through LDS, gates + c/h
        __syncthreads();
        float* asF = (float*)lds;
#pragma unroll
        for (int mt = 0; mt < 2; ++mt)
#pragma unroll
            for (int nt = 0; nt < 2; ++nt)
#pragma unroll
                for (int r = 0; r < 4; ++r) {
                    int row = wm * 32 + mt * 16 + quad * 4 + r;
                    int cc = wn * 32 + nt * 16 + l15;
                    asF[row * 64 + cc] = acc[mt][nt][r];
                }
        __syncthreads();

        float* out_t = out + (size_t)t * HH;
#pragma unroll
        for (int i = 0; i < 4; ++i) {
            int cell = i * 256 + tid;
            int row = cell >> 4;
            float ai  = asF[row * 64 + j15]      + bi;
            float af2 = asF[row * 64 + 16 + j15] + bf_;
            float ao  = asF[row * 64 + 32 + j15] + bo;
            float ag  = asF[row * 64 + 48 + j15] + bg;
            float iv = 1.f / (1.f + __expf(-ai));
            float fv = 1.f / (1.f + __expf(-af2));
            float ov = 1.f / (1.f + __expf(-ao));
            float gv = 1.f - 2.f / (__expf(2.f * ag) + 1.f);
            int nn = mi * 64 + row;
            size_t ci = (size_t)nn * HH + jj;
            float cold = c[ci];
            float cn = fv * cold + iv * gv;
            c[ci] = cn;
            float th = 1.f - 2.f / (__expf(2.f * cn) + 1.f);
            out_t[(size_t)nn * (TT * HH) + jj] = ov * th;
        }

        groupsync(ctr, 64u * (2 * t + 2));   // out/c of group g complete; lhsF free
    }
}

extern "C" void kernel_launch(void* const* d_in, const int* in_sizes, int n_in,
                              void* d_out, int out_size, void* d_ws, size_t ws_size,
                              hipStream_t stream) {
    const float* x     = (const float*)d_in[0];
    const float* A     = (const float*)d_in[1];
    const float* Wx    = (const float*)d_in[2];
    const float* Wh    = (const float*)d_in[3];
    const float* Wattn = (const float*)d_in[4];
    const float* b     = (const float*)d_in[5];
    float* out = (float*)d_out;

    char* w = (char*)d_ws;
    unsigned short* Wsw  = (unsigned short*)(w);                 // 25,165,824 B
    unsigned short* xF   = (unsigned short*)(w + 25165824);      // 33,554,432 B
    unsigned short* lhsF = (unsigned short*)(w + 58720256);      //  1,048,576 B
    unsigned short* Abf  = (unsigned short*)(w + 59768832);      //  8,388,608 B
    float* h0            = (float*)(w + 68157440);               //  1,048,576 B
    float* c             = (float*)(w + 69206016);               //  1,048,576 B
    unsigned* syncc      = (unsigned*)(w + 70254592);            //      4,096 B

    k_convW<<<6144, 256, 0, stream>>>(Wh, Wattn, Wx, Wsw);
    k_convX<<<1024, 256, 0, stream>>>(x, xF);
    k_convA_init<<<1024, 256, 0, stream>>>(A, Abf, h0, c, syncc);

    k_fused<<<256, 256, 0, stream>>>(Abf, xF, Wsw, b, h0, c, lhsF, syncc, out);
}

// Round 7
// 2962.887 us; speedup vs baseline: 1.9690x; 1.9690x over previous
//
#include <hip/hip_runtime.h>
#include <math.h>

#define NB 256
#define TT 64
#define DD 1024
#define HH 1024

typedef __attribute__((ext_vector_type(8))) short short8;
typedef __attribute__((ext_vector_type(4))) float floatx4;

__device__ inline unsigned short f2bf(float f) {
    unsigned int u = __builtin_bit_cast(unsigned int, f);
    u += 0x7fffu + ((u >> 16) & 1u);
    return (unsigned short)(u >> 16);
}
__device__ inline float bf2f(unsigned int h16) {
    unsigned int u = h16 << 16;
    return __builtin_bit_cast(float, u);
}

__device__ inline void async_copy16(const unsigned short* g, unsigned short* l) {
    __builtin_amdgcn_global_load_lds(
        (const __attribute__((address_space(1))) unsigned int*)(g),
        (__attribute__((address_space(3))) unsigned int*)(l), 16, 0, 0);
}

// device-scope group barrier for 64 blocks (one mi-group). Monotonic counter.
// R6 LESSON: polling with ACQUIRE at agent scope emits buffer_inv (full per-XCD
// L2 invalidate) EVERY poll -> continuous L2 thrash device-wide (5.8 ms run, all
// pipes <3% busy). Fix: RELAXED polls (no cache op), ONE acquire fence on exit.
// Entry: every thread drains vmcnt -> (a) its stores are in L2 before the leader's
// release-writeback, (b) counted-vmcnt math in the GEMM phase starts from 0.
__device__ inline void groupsync(unsigned* ctr, unsigned target) {
    asm volatile("s_waitcnt vmcnt(0)" ::: "memory");
    __syncthreads();
    if (threadIdx.x == 0) {
        __hip_atomic_fetch_add(ctr, 1u, __ATOMIC_RELEASE, __HIP_MEMORY_SCOPE_AGENT);
        while (__hip_atomic_load(ctr, __ATOMIC_RELAXED, __HIP_MEMORY_SCOPE_AGENT) < target)
            __builtin_amdgcn_s_sleep(4);
        __builtin_amdgcn_fence(__ATOMIC_ACQUIRE, "agent");  // single L1/L2 inv
    }
    __syncthreads();
}

// ---------------- conv W: fp32 [k][4096] -> bf16 B-fragment tiles, N_b=64 ----------
// Tile (nj 0..63, kc 0..47): 512 units of 16B; unit = kq*64 + cc (kq 0..7, cc 0..63);
// holds W[k = kc*64+kq*8 + j][col = (cc>>4)*1024 + nj*16 + (cc&15)], j=0..7.
__global__ void k_convW(const float* __restrict__ Wh,
                        const float* __restrict__ Wattn,
                        const float* __restrict__ Wx,
                        unsigned short* __restrict__ Wsw) {
    int u = blockIdx.x * 256 + threadIdx.x;  // 0 .. 64*48*512-1
    int tile = u >> 9;
    int nj = tile / 48, kc = tile % 48;
    int within = u & 511;
    int kq = within >> 6, cc = within & 63;
    int k = kc * 64 + kq * 8;
    int col = (cc >> 4) * 1024 + nj * 16 + (cc & 15);
    const float* src;
    if (k < 1024)       src = Wh    + (size_t)k * 4096 + col;
    else if (k < 2048)  src = Wattn + (size_t)(k - 1024) * 4096 + col;
    else                src = Wx    + (size_t)(k - 2048) * 4096 + col;
    unsigned int w[4];
#pragma unroll
    for (int j = 0; j < 4; ++j) {
        unsigned int lo = f2bf(src[(size_t)(2 * j) * 4096]);
        unsigned int hi = f2bf(src[(size_t)(2 * j + 1) * 4096]);
        w[j] = lo | (hi << 16);
    }
    ((uint4*)Wsw)[u] = make_uint4(w[0], w[1], w[2], w[3]);
}

// ---------------- conv x: fp32 [m][t][d] -> bf16 A-fragment layout -----------------
// xF unit index = t*32768 + kq*256 + m ; holds x[m][t][kq*8 + j], j=0..7.
__global__ __launch_bounds__(256) void k_convX(const float* __restrict__ x,
                                               unsigned short* __restrict__ xF) {
    const int t  = blockIdx.x >> 4;   // 0..63
    const int mb = blockIdx.x & 15;   // 0..15 (16 batch rows per block)
    const int tid = threadIdx.x;
    __shared__ unsigned short xb[16][1032];  // row stride 1032 shorts (pad)

#pragma unroll
    for (int mm = 0; mm < 16; ++mm) {
        int m = mb * 16 + mm;
        const float4* src = (const float4*)(x + (size_t)m * (TT * DD) + (size_t)t * DD);
        float4 v = src[tid];  // d = tid*4 .. tid*4+3
        unsigned int w0 = f2bf(v.x) | (f2bf(v.y) << 16);
        unsigned int w1 = f2bf(v.z) | (f2bf(v.w) << 16);
        *(uint2*)&xb[mm][tid * 4] = make_uint2(w0, w1);
    }
    __syncthreads();

#pragma unroll
    for (int i = 0; i < 8; ++i) {
        int u = i * 256 + tid;
        int kq = u >> 4, mm = u & 15;
        uint4 val = *(const uint4*)&xb[mm][kq * 8];
        size_t gu = (size_t)t * 32768 + (size_t)kq * 256 + mb * 16 + mm;
        ((uint4*)xF)[gu] = val;
    }
}

// ---------------- conv A -> bf16, plus h0 = c0 = mean; zero sync counters ----------
__global__ void k_convA_init(const float* __restrict__ A,
                             unsigned short* __restrict__ Abf,
                             float* __restrict__ h0,
                             unsigned* __restrict__ syncc) {
    int idx = blockIdx.x * 256 + threadIdx.x;  // n*1024 + h
    if (blockIdx.x == 0 && threadIdx.x < 4) syncc[threadIdx.x * 256] = 0u;
    const float4* ap = (const float4*)(A + (size_t)idx * 16);
    float4 v0 = ap[0], v1 = ap[1], v2 = ap[2], v3 = ap[3];
    float vs[16] = {v0.x, v0.y, v0.z, v0.w, v1.x, v1.y, v1.z, v1.w,
                    v2.x, v2.y, v2.z, v2.w, v3.x, v3.y, v3.z, v3.w};
    float s = 0.f;
    unsigned int w[8];
#pragma unroll
    for (int j = 0; j < 8; ++j) {
        s += vs[2 * j] + vs[2 * j + 1];
        w[j] = f2bf(vs[2 * j]) | (f2bf(vs[2 * j + 1]) << 16);
    }
    ((uint4*)Abf)[idx * 2]     = make_uint4(w[0], w[1], w[2], w[3]);
    ((uint4*)Abf)[idx * 2 + 1] = make_uint4(w[4], w[5], w[6], w[7]);
    s *= (1.f / 16.f);
    h0[idx] = s;
}

// ---------------- k_fused: PERSISTENT 64-step loop — attn + GEMM + gates -----------
// Grid = 256 blocks (1/CU). bid -> (g = bid>>6, nj = bid&63). Per-group 64-block
// sync (2/step); groups drift independently. R7 changes vs R6 (all symptom-driven):
//   1. groupsync: relaxed polls + single acquire fence (R6's per-poll acquire =
//      per-poll L2 invalidate = device-wide thrash).
//   2. a[4][16] reloaded from Abf each step (R6 hoist -> VGPR_Count 256).
//   3. c kept in 4 registers/thread: block (nj,g) owns the same 64x16 c-elements
//      every step -> block-private, never touches global memory.
// Phase 2 is the verified R0 GEMM pipeline byte-for-byte.
__global__ __launch_bounds__(256, 1) void k_fused(
    const unsigned short* __restrict__ Abf,
    const unsigned short* __restrict__ xF,
    const unsigned short* __restrict__ Wsw,
    const float* __restrict__ b,
    const float* __restrict__ h0,
    unsigned short* __restrict__ lhsF,
    unsigned* __restrict__ syncc,
    float* __restrict__ out) {
    const int bid = blockIdx.x;
    const int g = bid >> 6;          // mi-group 0..3
    const int nj = bid & 63;
    const int n = g * 64 + nj;       // attn row owned by this block
    const int mi = g;
    unsigned* ctr = syncc + g * 256; // 1 KB apart, one counter per group

    const int tid = threadIdx.x;
    const int lane = tid & 63, wave = tid >> 6;
    const int wm = wave & 1, wn = wave >> 1;
    const int l15 = lane & 15, quad = lane >> 4;
    const int waveBase = tid & ~63;

    __shared__ __align__(16) unsigned short lds[4 * 8192];  // 64 KB (GEMM + epilogue)
    __shared__ float wred[4 * 16];                          // attn reduction

    // ---- t-invariant scalars ----
    const unsigned short* wTile = Wsw + (size_t)nj * (48 * 512 * 8);
    const int j15 = tid & 15;
    const int jj = nj * 16 + j15;
    const float bi = b[jj], bf_ = b[1024 + jj], bo = b[2048 + jj], bg = b[3072 + jj];
    const size_t hu = ((size_t)(tid >> 1) * 256 + n) * 8 + (size_t)(tid & 1) * 4;
    const size_t au = ((size_t)(128 + (tid >> 1)) * 256 + n) * 8 + (size_t)(tid & 1) * 4;
    const uint4* ar = (const uint4*)(Abf + ((size_t)n * 1024 + tid * 4) * 16);

    // c in registers: thread owns (row = (i*256+tid)>>4, col jj), i = 0..3
    float c_reg[4];
#pragma unroll
    for (int i = 0; i < 4; ++i) {
        int row = (i * 256 + tid) >> 4;
        c_reg[i] = h0[(size_t)(mi * 64 + row) * HH + jj];
    }

    for (int t = 0; t < TT; ++t) {
        // ================= phase 1: attention for row n =================
        float a[4][16];
#pragma unroll
        for (int r = 0; r < 4; ++r) {
            uint4 p0 = ar[r * 2], p1 = ar[r * 2 + 1];
            unsigned int ws[8] = {p0.x, p0.y, p0.z, p0.w, p1.x, p1.y, p1.z, p1.w};
#pragma unroll
            for (int j = 0; j < 8; ++j) {
                a[r][2 * j]     = bf2f(ws[j] & 0xffffu);
                a[r][2 * j + 1] = bf2f(ws[j] >> 16);
            }
        }
        const float* hp = (t == 0) ? (h0 + (size_t)n * HH)
                                   : (out + (size_t)n * (TT * HH) + (size_t)(t - 1) * HH);
        float4 hv = *(const float4*)(hp + tid * 4);
        float hvv[4] = {hv.x, hv.y, hv.z, hv.w};
        float s[16];
#pragma unroll
        for (int l = 0; l < 16; ++l) {
            float tacc = 0.f;
#pragma unroll
            for (int r = 0; r < 4; ++r) tacc += hvv[r] * a[r][l];
            s[l] = tacc;
        }
#pragma unroll
        for (int off = 32; off > 0; off >>= 1) {
#pragma unroll
            for (int l = 0; l < 16; ++l) s[l] += __shfl_xor(s[l], off, 64);
        }
        if (lane == 0) {
#pragma unroll
            for (int l = 0; l < 16; ++l) wred[wave * 16 + l] = s[l];
        }
        __syncthreads();
        const float scale = 0.03125f;  // 1/sqrt(1024)
        float sv[16];
#pragma unroll
        for (int l = 0; l < 16; ++l)
            sv[l] = (wred[l] + wred[16 + l] + wred[32 + l] + wred[48 + l]) * scale;
        __syncthreads();   // wred reusable next step
        float mx = sv[0];
#pragma unroll
        for (int l = 1; l < 16; ++l) mx = fmaxf(mx, sv[l]);
        float e[16], esum = 0.f;
#pragma unroll
        for (int l = 0; l < 16; ++l) { e[l] = __expf(sv[l] - mx); esum += e[l]; }
        float inv = 1.f / esum;
#pragma unroll
        for (int l = 0; l < 16; ++l) e[l] *= inv;
        unsigned short hb[4], ab[4];
#pragma unroll
        for (int r = 0; r < 4; ++r) {
            float acc2 = 0.f;
#pragma unroll
            for (int l = 0; l < 16; ++l) acc2 += a[r][l] * e[l];
            ab[r] = f2bf(acc2);
            hb[r] = f2bf(hvv[r]);
        }
        *(uint2*)(lhsF + hu) = make_uint2(
            (unsigned)hb[0] | ((unsigned)hb[1] << 16),
            (unsigned)hb[2] | ((unsigned)hb[3] << 16));
        *(uint2*)(lhsF + au) = make_uint2(
            (unsigned)ab[0] | ((unsigned)ab[1] << 16),
            (unsigned)ab[2] | ((unsigned)ab[3] << 16));

        groupsync(ctr, 64u * (2 * t + 1));   // lhsF of group g complete

        // ================= phase 2: GEMM (nj, mi) + gates =================
        const unsigned short* xFt = xF + (size_t)t * 262144;

        floatx4 acc[2][2];
#pragma unroll
        for (int mt = 0; mt < 2; ++mt)
#pragma unroll
            for (int nt = 0; nt < 2; ++nt) acc[mt][nt] = (floatx4)0.f;

        auto stage = [&](int kc, int buf) {
            unsigned short* la = lds + (size_t)buf * 8192;
            unsigned short* lb = la + 4096;
            const unsigned short* as_ = (kc < 32)
                ? lhsF + ((size_t)(kc * 8) * 256 + (size_t)mi * 64) * 8
                : xFt + ((size_t)((kc - 32) * 8) * 256 + (size_t)mi * 64) * 8;
#pragma unroll
            for (int i = 0; i < 2; ++i) {
                int idx = i * 256 + tid;
                int kq = idx >> 6, mm = idx & 63;
                async_copy16(as_ + ((size_t)kq * 256 + mm) * 8,
                             la + (size_t)(i * 256 + waveBase) * 8);
            }
            const unsigned short* bs = wTile + (size_t)kc * 512 * 8;
#pragma unroll
            for (int i = 0; i < 2; ++i) {
                int idx = i * 256 + tid;
                async_copy16(bs + (size_t)idx * 8,
                             lb + (size_t)(i * 256 + waveBase) * 8);
            }
        };
        auto compute = [&](int buf) {
            const unsigned short* la = lds + (size_t)buf * 8192;
            const unsigned short* lb = la + 4096;
#pragma unroll
            for (int ks = 0; ks < 2; ++ks) {
                const int kqq = ks * 4 + quad;
                short8 af[2], bfr[2];
#pragma unroll
                for (int mt = 0; mt < 2; ++mt)
                    af[mt] = *(const short8*)(la + (size_t)(kqq * 64 + wm * 32 + mt * 16 + l15) * 8);
#pragma unroll
                for (int nt = 0; nt < 2; ++nt)
                    bfr[nt] = *(const short8*)(lb + (size_t)(kqq * 64 + wn * 32 + nt * 16 + l15) * 8);
#pragma unroll
                for (int mt = 0; mt < 2; ++mt)
#pragma unroll
                    for (int nt = 0; nt < 2; ++nt)
                        acc[mt][nt] = __builtin_amdgcn_mfma_f32_16x16x32_bf16(
                            af[mt], bfr[nt], acc[mt][nt], 0, 0, 0);
            }
        };

        stage(0, 0);
        stage(1, 1);
        stage(2, 2);  // 12 loads/wave outstanding (vmcnt==0 at phase entry)

#pragma unroll 4
        for (int kc = 0; kc < 45; ++kc) {
            asm volatile("s_waitcnt vmcnt(8)\n\ts_barrier" ::: "memory");
            stage(kc + 3, (kc + 3) & 3);
            compute(kc & 3);
        }
        asm volatile("s_waitcnt vmcnt(8)\n\ts_barrier" ::: "memory");
        compute(45 & 3);
        asm volatile("s_waitcnt vmcnt(4)\n\ts_barrier" ::: "memory");
        compute(46 & 3);
        asm volatile("s_waitcnt vmcnt(0)\n\ts_barrier" ::: "memory");
        compute(47 & 3);

        // epilogue: exchange 64x64 fp32 tile through LDS, gates + c(reg)/h
        __syncthreads();
        float* asF = (float*)lds;
#pragma unroll
        for (int mt = 0; mt < 2; ++mt)
#pragma unroll
            for (int nt = 0; nt < 2; ++nt)
#pragma unroll
                for (int r = 0; r < 4; ++r) {
                    int row = wm * 32 + mt * 16 + quad * 4 + r;
                    int cc = wn * 32 + nt * 16 + l15;
                    asF[row * 64 + cc] = acc[mt][nt][r];
                }
        __syncthreads();

        float* out_t = out + (size_t)t * HH;
#pragma unroll
        for (int i = 0; i < 4; ++i) {
            int cell = i * 256 + tid;
            int row = cell >> 4;
            float ai  = asF[row * 64 + j15]      + bi;
            float af2 = asF[row * 64 + 16 + j15] + bf_;
            float ao  = asF[row * 64 + 32 + j15] + bo;
            float ag  = asF[row * 64 + 48 + j15] + bg;
            float iv = 1.f / (1.f + __expf(-ai));
            float fv = 1.f / (1.f + __expf(-af2));
            float ov = 1.f / (1.f + __expf(-ao));
            float gv = 1.f - 2.f / (__expf(2.f * ag) + 1.f);
            float cn = fv * c_reg[i] + iv * gv;
            c_reg[i] = cn;
            float th = 1.f - 2.f / (__expf(2.f * cn) + 1.f);
            int nn = mi * 64 + row;
            out_t[(size_t)nn * (TT * HH) + jj] = ov * th;
        }

        groupsync(ctr, 64u * (2 * t + 2));   // out of group g visible; lhsF free
    }
}

extern "C" void kernel_launch(void* const* d_in, const int* in_sizes, int n_in,
                              void* d_out, int out_size, void* d_ws, size_t ws_size,
                              hipStream_t stream) {
    const float* x     = (const float*)d_in[0];
    const float* A     = (const float*)d_in[1];
    const float* Wx    = (const float*)d_in[2];
    const float* Wh    = (const float*)d_in[3];
    const float* Wattn = (const float*)d_in[4];
    const float* b     = (const float*)d_in[5];
    float* out = (float*)d_out;

    char* w = (char*)d_ws;
    unsigned short* Wsw  = (unsigned short*)(w);                 // 25,165,824 B
    unsigned short* xF   = (unsigned short*)(w + 25165824);      // 33,554,432 B
    unsigned short* lhsF = (unsigned short*)(w + 58720256);      //  1,048,576 B
    unsigned short* Abf  = (unsigned short*)(w + 59768832);      //  8,388,608 B
    float* h0            = (float*)(w + 68157440);               //  1,048,576 B
    unsigned* syncc      = (unsigned*)(w + 69206016);            //      4,096 B

    k_convW<<<6144, 256, 0, stream>>>(Wh, Wattn, Wx, Wsw);
    k_convX<<<1024, 256, 0, stream>>>(x, xF);
    k_convA_init<<<1024, 256, 0, stream>>>(A, Abf, h0, syncc);

    k_fused<<<256, 256, 0, stream>>>(Abf, xF, Wsw, b, h0, lhsF, syncc, out);
}

// Round 8
// 1616.571 us; speedup vs baseline: 3.6089x; 1.8328x over previous
//
#include <hip/hip_runtime.h>
#include <math.h>

#define NB 256
#define TT 64
#define DD 1024
#define HH 1024

typedef __attribute__((ext_vector_type(8))) short short8;
typedef __attribute__((ext_vector_type(4))) float floatx4;
typedef unsigned long long u64;

__device__ inline unsigned short f2bf(float f) {
    unsigned int u = __builtin_bit_cast(unsigned int, f);
    u += 0x7fffu + ((u >> 16) & 1u);
    return (unsigned short)(u >> 16);
}
__device__ inline float bf2f(unsigned int h16) {
    unsigned int u = h16 << 16;
    return __builtin_bit_cast(float, u);
}

__device__ inline void async_copy16(const unsigned short* g, unsigned short* l) {
    __builtin_amdgcn_global_load_lds(
        (const __attribute__((address_space(1))) unsigned int*)(g),
        (__attribute__((address_space(3))) unsigned int*)(l), 16, 0, 0);
}

// ---- coherent (cache-bypassing) accessors: agent-scope relaxed atomics. These are
// serviced at the device coherence point (R7's poll proved relaxed-agent loads see
// remote writes), so NO acquire/release cache maintenance is needed anywhere.
__device__ inline u64 co_load(const u64* p) {
    return __hip_atomic_load(p, __ATOMIC_RELAXED, __HIP_MEMORY_SCOPE_AGENT);
}
__device__ inline void co_store(u64* p, u64 v) {
    __hip_atomic_store(p, v, __ATOMIC_RELAXED, __HIP_MEMORY_SCOPE_AGENT);
}
__device__ inline void co_storef(float* p, float v) {
    __hip_atomic_store(p, v, __ATOMIC_RELAXED, __HIP_MEMORY_SCOPE_AGENT);
}

// group barrier, ZERO cache maintenance. Per-thread vmcnt(0) drain guarantees all
// bypass-stores are acked at the coherence point before the leader's (relaxed)
// increment becomes visible -> observers of count>=target see the data.
// R6 lesson: acquire-per-poll = buffer_inv storm. R7 lesson: release adds
// buffer_wbl2 (full 4MB L2 scan) per block per sync -> ~30us/step. Both gone.
__device__ inline void groupsync(unsigned* ctr, unsigned target) {
    asm volatile("s_waitcnt vmcnt(0)" ::: "memory");
    __syncthreads();
    if (threadIdx.x == 0) {
        __hip_atomic_fetch_add(ctr, 1u, __ATOMIC_RELAXED, __HIP_MEMORY_SCOPE_AGENT);
        while (__hip_atomic_load(ctr, __ATOMIC_RELAXED, __HIP_MEMORY_SCOPE_AGENT) < target)
            __builtin_amdgcn_s_sleep(4);
    }
    __syncthreads();
}

// ---------------- conv W: fp32 [k][4096] -> bf16 B-fragment tiles, N_b=64 ----------
__global__ void k_convW(const float* __restrict__ Wh,
                        const float* __restrict__ Wattn,
                        const float* __restrict__ Wx,
                        unsigned short* __restrict__ Wsw) {
    int u = blockIdx.x * 256 + threadIdx.x;  // 0 .. 64*48*512-1
    int tile = u >> 9;
    int nj = tile / 48, kc = tile % 48;
    int within = u & 511;
    int kq = within >> 6, cc = within & 63;
    int k = kc * 64 + kq * 8;
    int col = (cc >> 4) * 1024 + nj * 16 + (cc & 15);
    const float* src;
    if (k < 1024)       src = Wh    + (size_t)k * 4096 + col;
    else if (k < 2048)  src = Wattn + (size_t)(k - 1024) * 4096 + col;
    else                src = Wx    + (size_t)(k - 2048) * 4096 + col;
    unsigned int w[4];
#pragma unroll
    for (int j = 0; j < 4; ++j) {
        unsigned int lo = f2bf(src[(size_t)(2 * j) * 4096]);
        unsigned int hi = f2bf(src[(size_t)(2 * j + 1) * 4096]);
        w[j] = lo | (hi << 16);
    }
    ((uint4*)Wsw)[u] = make_uint4(w[0], w[1], w[2], w[3]);
}

// ---------------- conv x: fp32 [m][t][d] -> bf16 A-fragment layout -----------------
__global__ __launch_bounds__(256) void k_convX(const float* __restrict__ x,
                                               unsigned short* __restrict__ xF) {
    const int t  = blockIdx.x >> 4;
    const int mb = blockIdx.x & 15;
    const int tid = threadIdx.x;
    __shared__ unsigned short xb[16][1032];

#pragma unroll
    for (int mm = 0; mm < 16; ++mm) {
        int m = mb * 16 + mm;
        const float4* src = (const float4*)(x + (size_t)m * (TT * DD) + (size_t)t * DD);
        float4 v = src[tid];
        unsigned int w0 = f2bf(v.x) | (f2bf(v.y) << 16);
        unsigned int w1 = f2bf(v.z) | (f2bf(v.w) << 16);
        *(uint2*)&xb[mm][tid * 4] = make_uint2(w0, w1);
    }
    __syncthreads();

#pragma unroll
    for (int i = 0; i < 8; ++i) {
        int u = i * 256 + tid;
        int kq = u >> 4, mm = u & 15;
        uint4 val = *(const uint4*)&xb[mm][kq * 8];
        size_t gu = (size_t)t * 32768 + (size_t)kq * 256 + mb * 16 + mm;
        ((uint4*)xF)[gu] = val;
    }
}

// ---------------- conv A -> bf16, plus h0 = c0 = mean; zero sync counters ----------
__global__ void k_convA_init(const float* __restrict__ A,
                             unsigned short* __restrict__ Abf,
                             float* __restrict__ h0,
                             unsigned* __restrict__ syncc) {
    int idx = blockIdx.x * 256 + threadIdx.x;
    if (blockIdx.x == 0 && threadIdx.x < 4) syncc[threadIdx.x * 256] = 0u;
    const float4* ap = (const float4*)(A + (size_t)idx * 16);
    float4 v0 = ap[0], v1 = ap[1], v2 = ap[2], v3 = ap[3];
    float vs[16] = {v0.x, v0.y, v0.z, v0.w, v1.x, v1.y, v1.z, v1.w,
                    v2.x, v2.y, v2.z, v2.w, v3.x, v3.y, v3.z, v3.w};
    float s = 0.f;
    unsigned int w[8];
#pragma unroll
    for (int j = 0; j < 8; ++j) {
        s += vs[2 * j] + vs[2 * j + 1];
        w[j] = f2bf(vs[2 * j]) | (f2bf(vs[2 * j + 1]) << 16);
    }
    ((uint4*)Abf)[idx * 2]     = make_uint4(w[0], w[1], w[2], w[3]);
    ((uint4*)Abf)[idx * 2 + 1] = make_uint4(w[4], w[5], w[6], w[7]);
    s *= (1.f / 16.f);
    h0[idx] = s;
}

// ---------------- k_fused: persistent 64-step loop, fence-free coherent sync -------
// Grid 256 (1/CU). bid -> (g = bid>>6, nj = bid&63); groups independent.
// Per step: attn -> lhsF (bypass stores) -> phase X GEMM (kc 32..47, xF: R0-exact
// async pipeline, no coherence needed, runs BEFORE sync#1 to absorb arrival spread)
// -> sync#1 -> phase Y GEMM (kc 0..31: A from lhsF via bypass loads, B cached
// (L2-resident W), reg->LDS, 3-deep hand-rotated register sets, compiler-managed,
// NO asm vmcnt (the R5 mixed-queue bug class)) -> gates (c in regs, out via bypass
// stores) -> sync#2. With no cache maintenance anywhere, W/Abf/xF stay L2-resident
// across the whole 64 steps (bid%8 pins each nj's W-tile to one XCD, 3 MB/XCD).
__global__ __launch_bounds__(256, 1) void k_fused(
    const unsigned short* __restrict__ Abf,
    const unsigned short* __restrict__ xF,
    const unsigned short* __restrict__ Wsw,
    const float* __restrict__ b,
    const float* __restrict__ h0,
    unsigned short* __restrict__ lhsF,
    unsigned* __restrict__ syncc,
    float* __restrict__ out) {
    const int bid = blockIdx.x;
    const int g = bid >> 6;
    const int nj = bid & 63;
    const int n = g * 64 + nj;
    const int mi = g;
    unsigned* ctr = syncc + g * 256;

    const int tid = threadIdx.x;
    const int lane = tid & 63, wave = tid >> 6;
    const int wm = wave & 1, wn = wave >> 1;
    const int l15 = lane & 15, quad = lane >> 4;
    const int waveBase = tid & ~63;

    __shared__ __align__(16) unsigned short lds[4 * 8192];  // 64 KB
    __shared__ float wred[4 * 16];

    const unsigned short* wTile = Wsw + (size_t)nj * (48 * 512 * 8);
    const int j15 = tid & 15;
    const int jj = nj * 16 + j15;
    const float bi = b[jj], bf_ = b[1024 + jj], bo = b[2048 + jj], bg = b[3072 + jj];
    const size_t hu = ((size_t)(tid >> 1) * 256 + n) * 8 + (size_t)(tid & 1) * 4;
    const size_t au = ((size_t)(128 + (tid >> 1)) * 256 + n) * 8 + (size_t)(tid & 1) * 4;
    const uint4* ar = (const uint4*)(Abf + ((size_t)n * 1024 + tid * 4) * 16);

    // c in registers (block-private: same 64x16 c-elements every step)
    float c_reg[4];
#pragma unroll
    for (int i = 0; i < 4; ++i) {
        int row = (i * 256 + tid) >> 4;
        c_reg[i] = h0[(size_t)(mi * 64 + row) * HH + jj];
    }

    floatx4 acc[2][2];

    auto compute = [&](int buf) {
        const unsigned short* la = lds + (size_t)buf * 8192;
        const unsigned short* lb = la + 4096;
#pragma unroll
        for (int ks = 0; ks < 2; ++ks) {
            const int kqq = ks * 4 + quad;
            short8 af[2], bfr[2];
#pragma unroll
            for (int mt = 0; mt < 2; ++mt)
                af[mt] = *(const short8*)(la + (size_t)(kqq * 64 + wm * 32 + mt * 16 + l15) * 8);
#pragma unroll
            for (int nt = 0; nt < 2; ++nt)
                bfr[nt] = *(const short8*)(lb + (size_t)(kqq * 64 + wn * 32 + nt * 16 + l15) * 8);
#pragma unroll
            for (int mt = 0; mt < 2; ++mt)
#pragma unroll
                for (int nt = 0; nt < 2; ++nt)
                    acc[mt][nt] = __builtin_amdgcn_mfma_f32_16x16x32_bf16(
                        af[mt], bfr[nt], acc[mt][nt], 0, 0, 0);
        }
    };

    // phase-Y register set (static member offsets; never runtime-indexed)
    struct SetT { u64 a0, a1, a2, a3; uint4 b0, b1; };
    auto loadSet = [&](SetT& s, int kc) {
        {
            int idx = tid, kq = idx >> 6, mm = idx & 63;
            const u64* p = (const u64*)(lhsF +
                ((size_t)(kc * 8 + kq) * 256 + (size_t)mi * 64 + mm) * 8);
            s.a0 = co_load(p);
            s.a1 = co_load(p + 1);
            s.b0 = *(const uint4*)(wTile + ((size_t)kc * 512 + idx) * 8);
        }
        {
            int idx = 256 + tid, kq = idx >> 6, mm = idx & 63;
            const u64* p = (const u64*)(lhsF +
                ((size_t)(kc * 8 + kq) * 256 + (size_t)mi * 64 + mm) * 8);
            s.a2 = co_load(p);
            s.a3 = co_load(p + 1);
            s.b1 = *(const uint4*)(wTile + ((size_t)kc * 512 + idx) * 8);
        }
    };
    auto writeSet = [&](const SetT& s, int buf) {
        unsigned short* la = lds + (size_t)buf * 8192;
        unsigned short* lb = la + 4096;
        ((uint4*)la)[tid] = make_uint4((unsigned)s.a0, (unsigned)(s.a0 >> 32),
                                       (unsigned)s.a1, (unsigned)(s.a1 >> 32));
        ((uint4*)la)[256 + tid] = make_uint4((unsigned)s.a2, (unsigned)(s.a2 >> 32),
                                             (unsigned)s.a3, (unsigned)(s.a3 >> 32));
        ((uint4*)lb)[tid] = s.b0;
        ((uint4*)lb)[256 + tid] = s.b1;
    };

    for (int t = 0; t < TT; ++t) {
        // ================= phase 1: attention for row n =================
        float a[4][16];
#pragma unroll
        for (int r = 0; r < 4; ++r) {
            uint4 p0 = ar[r * 2], p1 = ar[r * 2 + 1];
            unsigned int ws[8] = {p0.x, p0.y, p0.z, p0.w, p1.x, p1.y, p1.z, p1.w};
#pragma unroll
            for (int j = 0; j < 8; ++j) {
                a[r][2 * j]     = bf2f(ws[j] & 0xffffu);
                a[r][2 * j + 1] = bf2f(ws[j] >> 16);
            }
        }
        // h-read: bypass loads (peer blocks wrote out on other XCDs)
        const float* hp = (t == 0) ? (h0 + (size_t)n * HH)
                                   : (out + (size_t)n * (TT * HH) + (size_t)(t - 1) * HH);
        u64 u0 = co_load((const u64*)(hp + tid * 4));
        u64 u1 = co_load((const u64*)(hp + tid * 4) + 1);
        float hvv[4] = {
            __builtin_bit_cast(float, (unsigned)(u0 & 0xffffffffu)),
            __builtin_bit_cast(float, (unsigned)(u0 >> 32)),
            __builtin_bit_cast(float, (unsigned)(u1 & 0xffffffffu)),
            __builtin_bit_cast(float, (unsigned)(u1 >> 32))};
        float s[16];
#pragma unroll
        for (int l = 0; l < 16; ++l) {
            float tacc = 0.f;
#pragma unroll
            for (int r = 0; r < 4; ++r) tacc += hvv[r] * a[r][l];
            s[l] = tacc;
        }
#pragma unroll
        for (int off = 32; off > 0; off >>= 1) {
#pragma unroll
            for (int l = 0; l < 16; ++l) s[l] += __shfl_xor(s[l], off, 64);
        }
        if (lane == 0) {
#pragma unroll
            for (int l = 0; l < 16; ++l) wred[wave * 16 + l] = s[l];
        }
        __syncthreads();
        const float scale = 0.03125f;
        float sv[16];
#pragma unroll
        for (int l = 0; l < 16; ++l)
            sv[l] = (wred[l] + wred[16 + l] + wred[32 + l] + wred[48 + l]) * scale;
        __syncthreads();
        float mx = sv[0];
#pragma unroll
        for (int l = 1; l < 16; ++l) mx = fmaxf(mx, sv[l]);
        float e[16], esum = 0.f;
#pragma unroll
        for (int l = 0; l < 16; ++l) { e[l] = __expf(sv[l] - mx); esum += e[l]; }
        float inv = 1.f / esum;
#pragma unroll
        for (int l = 0; l < 16; ++l) e[l] *= inv;
        unsigned short hb[4], ab[4];
#pragma unroll
        for (int r = 0; r < 4; ++r) {
            float acc2 = 0.f;
#pragma unroll
            for (int l = 0; l < 16; ++l) acc2 += a[r][l] * e[l];
            ab[r] = f2bf(acc2);
            hb[r] = f2bf(hvv[r]);
        }
        // lhsF: bypass stores (read by 64 blocks across XCDs)
        u64 hw = (u64)((unsigned)hb[0] | ((unsigned)hb[1] << 16)) |
                 ((u64)((unsigned)hb[2] | ((unsigned)hb[3] << 16)) << 32);
        u64 aw = (u64)((unsigned)ab[0] | ((unsigned)ab[1] << 16)) |
                 ((u64)((unsigned)ab[2] | ((unsigned)ab[3] << 16)) << 32);
        co_store((u64*)(lhsF + hu), hw);
        co_store((u64*)(lhsF + au), aw);

#pragma unroll
        for (int mt = 0; mt < 2; ++mt)
#pragma unroll
            for (int nt = 0; nt < 2; ++nt) acc[mt][nt] = (floatx4)0.f;

        // ===== phase X: kc 32..47 (xF only), R0-exact async pipeline =====
        const unsigned short* xFt = xF + (size_t)t * 262144;
        auto stageX = [&](int kc, int buf) {
            unsigned short* la = lds + (size_t)buf * 8192;
            unsigned short* lb = la + 4096;
            const unsigned short* as_ =
                xFt + ((size_t)((kc - 32) * 8) * 256 + (size_t)mi * 64) * 8;
#pragma unroll
            for (int i = 0; i < 2; ++i) {
                int idx = i * 256 + tid;
                int kq = idx >> 6, mm = idx & 63;
                async_copy16(as_ + ((size_t)kq * 256 + mm) * 8,
                             la + (size_t)(i * 256 + waveBase) * 8);
            }
            const unsigned short* bs = wTile + (size_t)kc * 512 * 8;
#pragma unroll
            for (int i = 0; i < 2; ++i) {
                int idx = i * 256 + tid;
                async_copy16(bs + (size_t)idx * 8,
                             lb + (size_t)(i * 256 + waveBase) * 8);
            }
        };

        // clean queue so the counted vmcnt below is exact (lhsF store acks drain)
        asm volatile("s_waitcnt vmcnt(0)" ::: "memory");
        __syncthreads();   // phase-1 LDS (wred) done; lds bufs free
        stageX(32, 0);
        stageX(33, 1);
        stageX(34, 2);
#pragma unroll 2
        for (int kc = 32; kc < 45; ++kc) {
            asm volatile("s_waitcnt vmcnt(8)\n\ts_barrier" ::: "memory");
            stageX(kc + 3, (kc + 3) & 3);
            compute(kc & 3);
        }
        asm volatile("s_waitcnt vmcnt(8)\n\ts_barrier" ::: "memory");
        compute(45 & 3);
        asm volatile("s_waitcnt vmcnt(4)\n\ts_barrier" ::: "memory");
        compute(46 & 3);
        asm volatile("s_waitcnt vmcnt(0)\n\ts_barrier" ::: "memory");
        compute(47 & 3);

        groupsync(ctr, 64u * (2 * t + 1));   // lhsF of group g complete

        // ===== phase Y: kc 0..31 (lhsF+Wh|Wattn), compiler-managed =====
        SetT s0, s1, s2;
        loadSet(s0, 0);
        loadSet(s1, 1);
        loadSet(s2, 2);
        writeSet(s0, 0);
        __syncthreads();
        for (int b3 = 0; b3 < 10; ++b3) {
            int kc = b3 * 3;
            compute(kc & 1);
            __syncthreads();
            writeSet(s1, (kc + 1) & 1);
            loadSet(s0, kc + 3);
            __syncthreads();

            compute((kc + 1) & 1);
            __syncthreads();
            writeSet(s2, (kc + 2) & 1);
            loadSet(s1, kc + 4);
            __syncthreads();

            compute((kc + 2) & 1);
            __syncthreads();
            writeSet(s0, (kc + 3) & 1);
            if (kc + 5 <= 31) loadSet(s2, kc + 5);
            __syncthreads();
        }
        compute(0);          // chunk 30
        __syncthreads();
        writeSet(s1, 1);     // chunk 31 (loaded at b3=9)
        __syncthreads();
        compute(1);          // chunk 31

        // ===== epilogue: LDS exchange, gates, c(reg), out via bypass stores =====
        __syncthreads();
        float* asF = (float*)lds;
#pragma unroll
        for (int mt = 0; mt < 2; ++mt)
#pragma unroll
            for (int nt = 0; nt < 2; ++nt)
#pragma unroll
                for (int r = 0; r < 4; ++r) {
                    int row = wm * 32 + mt * 16 + quad * 4 + r;
                    int cc = wn * 32 + nt * 16 + l15;
                    asF[row * 64 + cc] = acc[mt][nt][r];
                }
        __syncthreads();

        float* out_t = out + (size_t)t * HH;
#pragma unroll
        for (int i = 0; i < 4; ++i) {
            int cell = i * 256 + tid;
            int row = cell >> 4;
            float ai  = asF[row * 64 + j15]      + bi;
            float af2 = asF[row * 64 + 16 + j15] + bf_;
            float ao  = asF[row * 64 + 32 + j15] + bo;
            float ag  = asF[row * 64 + 48 + j15] + bg;
            float iv = 1.f / (1.f + __expf(-ai));
            float fv = 1.f / (1.f + __expf(-af2));
            float ov = 1.f / (1.f + __expf(-ao));
            float gv = 1.f - 2.f / (__expf(2.f * ag) + 1.f);
            float cn = fv * c_reg[i] + iv * gv;
            c_reg[i] = cn;
            float th = 1.f - 2.f / (__expf(2.f * cn) + 1.f);
            int nn = mi * 64 + row;
            co_storef(out_t + (size_t)nn * (TT * HH) + jj, ov * th);
        }

        groupsync(ctr, 64u * (2 * t + 2));   // out of group g visible; lhsF free
    }
}

extern "C" void kernel_launch(void* const* d_in, const int* in_sizes, int n_in,
                              void* d_out, int out_size, void* d_ws, size_t ws_size,
                              hipStream_t stream) {
    const float* x     = (const float*)d_in[0];
    const float* A     = (const float*)d_in[1];
    const float* Wx    = (const float*)d_in[2];
    const float* Wh    = (const float*)d_in[3];
    const float* Wattn = (const float*)d_in[4];
    const float* b     = (const float*)d_in[5];
    float* out = (float*)d_out;

    char* w = (char*)d_ws;
    unsigned short* Wsw  = (unsigned short*)(w);                 // 25,165,824 B
    unsigned short* xF   = (unsigned short*)(w + 25165824);      // 33,554,432 B
    unsigned short* lhsF = (unsigned short*)(w + 58720256);      //  1,048,576 B
    unsigned short* Abf  = (unsigned short*)(w + 59768832);      //  8,388,608 B
    float* h0            = (float*)(w + 68157440);               //  1,048,576 B
    unsigned* syncc      = (unsigned*)(w + 69206016);            //      4,096 B

    k_convW<<<6144, 256, 0, stream>>>(Wh, Wattn, Wx, Wsw);
    k_convX<<<1024, 256, 0, stream>>>(x, xF);
    k_convA_init<<<1024, 256, 0, stream>>>(A, Abf, h0, syncc);

    k_fused<<<256, 256, 0, stream>>>(Abf, xF, Wsw, b, h0, lhsF, syncc, out);
}